// Round 13
// baseline (106.211 us; speedup 1.0000x reference)
//
#include <hip/hip_runtime.h>
#include <math.h>

#define NW 4  // waves per block; one matrix per wave

typedef __attribute__((ext_vector_type(16))) float f32x16;
typedef __attribute__((ext_vector_type(4))) float f32x4;
typedef __attribute__((ext_vector_type(8))) short s16x8;
typedef __attribute__((ext_vector_type(4))) unsigned int u32x4;

struct Frag { s16x8 h0, h1, l0, l1; };  // bf16 hi/lo, k-halves 0..15 / 16..31
struct FragH { s16x8 h0, h1; };         // bf16 RNE hi only

__device__ __forceinline__ f32x16 mfma32(s16x8 a, s16x8 b, f32x16 c) {
  return __builtin_amdgcn_mfma_f32_32x32x16_bf16(a, b, c, 0, 0, 0);
}

// Full split product: XhYh + XhYl + XlYh (rel ~2^-17)
__device__ __forceinline__ f32x16 matmul(const Frag& X, const Frag& Y, f32x16 acc) {
  acc = mfma32(X.h0, Y.h0, acc);
  acc = mfma32(X.h1, Y.h1, acc);
  acc = mfma32(X.h0, Y.l0, acc);
  acc = mfma32(X.h1, Y.l1, acc);
  acc = mfma32(X.l0, Y.h0, acc);
  acc = mfma32(X.l1, Y.h1, acc);
  return acc;
}

// Half-split product: Xh(Yh+Yl) — X's lo dropped (X's weight in result is small)
__device__ __forceinline__ f32x16 matmul_hb(const FragH& X, const Frag& Y, f32x16 acc) {
  acc = mfma32(X.h0, Y.h0, acc);
  acc = mfma32(X.h1, Y.h1, acc);
  acc = mfma32(X.h0, Y.l0, acc);
  acc = mfma32(X.h1, Y.l1, acc);
  return acc;
}

// RNE-bf16-only squaring (rel ~2^-8; last squarings only)
__device__ __forceinline__ f32x16 sq_h(const FragH& X, f32x16 acc) {
  acc = mfma32(X.h0, X.h0, acc);
  acc = mfma32(X.h1, X.h1, acc);
  return acc;
}

__device__ __forceinline__ s16x8 mk(uint a, uint b, uint c, uint d) {
  union { u32x4 u; s16x8 s; } t;
  t.u = (u32x4){a, b, c, d};
  return t.s;
}

// C/D layout (col=lane&31, row=(reg&3)+8*(reg>>2)+4*hi) -> A/B fragment
// (row=lane&31, k contiguous) via symmetry; 8 permlane32_swap, both outputs used.
__device__ __forceinline__ void permstage(const f32x16 c, uint e[16]) {
#pragma unroll
  for (int f = 0; f < 2; ++f)
#pragma unroll
    for (int j = 0; j < 4; ++j) {
      auto r = __builtin_amdgcn_permlane32_swap(
          __float_as_uint(c[8 * f + 4 + j]), __float_as_uint(c[8 * f + j]),
          false, false);
      e[8 * f + j] = r[1];
      e[8 * f + 4 + j] = r[0];
    }
}

// Full split convert: hi = RNE bf16 (cvt_pk), lo = RNE(residual)
__device__ __forceinline__ Frag convert(const f32x16 c) {
  uint e[16];
  permstage(c, e);
  uint hw[8], lw[8];
#pragma unroll
  for (int p = 0; p < 8; ++p) {
    float x0 = __uint_as_float(e[2 * p]);
    float x1 = __uint_as_float(e[2 * p + 1]);
    uint hp;
    asm("v_cvt_pk_bf16_f32 %0, %1, %2" : "=v"(hp) : "v"(x0), "v"(x1));
    float l0 = x0 - __uint_as_float(hp << 16);
    float l1 = x1 - __uint_as_float(hp & 0xffff0000u);
    uint lp;
    asm("v_cvt_pk_bf16_f32 %0, %1, %2" : "=v"(lp) : "v"(l0), "v"(l1));
    hw[p] = hp;
    lw[p] = lp;
  }
  Frag F;
  F.h0 = mk(hw[0], hw[1], hw[2], hw[3]);
  F.h1 = mk(hw[4], hw[5], hw[6], hw[7]);
  F.l0 = mk(lw[0], lw[1], lw[2], lw[3]);
  F.l1 = mk(lw[4], lw[5], lw[6], lw[7]);
  return F;
}

// Cheap convert: RNE bf16 hi only
__device__ __forceinline__ FragH convert_h(const f32x16 c) {
  uint e[16];
  permstage(c, e);
  uint hw[8];
#pragma unroll
  for (int p = 0; p < 8; ++p) {
    float x0 = __uint_as_float(e[2 * p]);
    float x1 = __uint_as_float(e[2 * p + 1]);
    uint hp;
    asm("v_cvt_pk_bf16_f32 %0, %1, %2" : "=v"(hp) : "v"(x0), "v"(x1));
    hw[p] = hp;
  }
  FragH F;
  F.h0 = mk(hw[0], hw[1], hw[2], hw[3]);
  F.h1 = mk(hw[4], hw[5], hw[6], hw[7]);
  return F;
}

// Load A in C-layout via symmetry: reg 4g+q <- A[c32][8g+4hi+q]
__device__ __forceinline__ f32x16 loadA(const float* __restrict__ p, uint c32, uint hi) {
  f32x16 A;
#pragma unroll
  for (int g = 0; g < 4; ++g) {
    float4 v = *(const float4*)(p + c32 * 32 + g * 8 + hi * 4);
    A[4 * g + 0] = v.x; A[4 * g + 1] = v.y; A[4 * g + 2] = v.z; A[4 * g + 3] = v.w;
  }
  return A;
}

__global__ __launch_bounds__(256, 4) void expm32_kernel(const float* __restrict__ in,
                                                        float* __restrict__ out, int nmat) {
  const uint lane = threadIdx.x & 63;
  const uint wid = threadIdx.x >> 6;
  const uint c32 = lane & 31, hi = lane >> 5;
  const uint m = blockIdx.x * NW + wid;
  if (m >= (uint)nmat) return;
  const float* src = in + (size_t)m * 1024u;
  float* dst = out + (size_t)m * 1024u;

  // Diagonal mask vector (one reg per lane when hi matches)
  const uint rd = (c32 & 3) | ((c32 >> 1) & 12);
  const bool dval = (hi == ((c32 >> 2) & 1));
  f32x16 dv;
#pragma unroll
  for (int r = 0; r < 16; ++r) dv[r] = (dval && (uint)r == rd) ? 1.f : 0.f;

  f32x16 A = loadA(src, c32, hi);

  // ---- NORM-HOIST: ||A||_F^2 -> s, before (independent of) the A2 MFMA ----
  float ss = 0.f;
#pragma unroll
  for (int r = 0; r < 16; ++r) ss = fmaf(A[r], A[r], ss);
#pragma unroll
  for (int o = 32; o > 0; o >>= 1) ss += __shfl_xor(ss, o, 64);
  int s;
  {
    float v = ss * (1.f / 9.f);  // (||A||_F/theta)^2, theta=3; lambda<=||A||_F
    uint u = __float_as_uint(v);
    int e = (int)((u >> 23) & 255) - 127 + (((u & 0x7fffffu) != 0u) ? 1 : 0);
    s = (e + 1) >> 1;  // ceil(e/2): 4^s >= v
    s = (s < 0) ? 0 : (s > 15 ? 15 : s);
  }
  const float sc = __uint_as_float((uint)(127 - s) << 23);  // exact 2^-s
  const float sc2 = sc * sc;

  // ---- A2 = A*A (unscaled, full split precision) ----
  Frag FA = convert(A);
  f32x16 z0;
#pragma unroll
  for (int r = 0; r < 16; ++r) z0[r] = 0.f;
  f32x16 A2 = matmul(FA, FA, z0);

  // ---- FB = frag(A2') [split]; P3 = c6 I + c7 A' + c8 A2' [cheap] ----
  f32x16 B2;
#pragma unroll
  for (int r = 0; r < 16; ++r) B2[r] = A2[r] * sc2;
  Frag FB = convert(B2);
  const float c7s = (1.f / 5040.f) * sc, c8f = 1.f / 40320.f;
  f32x16 z;
#pragma unroll
  for (int r = 0; r < 16; ++r)
    z[r] = fmaf(c8f, B2[r], fmaf(c7s, A[r], (1.f / 720.f) * dv[r]));
  FragH FP = convert_h(z);

  // ---- 3 Horner steps: P <- Ph*A2' + cI*I + cA*A' (hi-only P operand) ----
  const float cIs[3] = {1.f / 24.f, 0.5f, 1.f};
  const float cAs[3] = {1.f / 120.f, 1.f / 6.f, 1.f};
  f32x16 R;
#pragma unroll
  for (int st = 0; st < 3; ++st) {
    const float cA = cAs[st] * sc;
#pragma unroll
    for (int r = 0; r < 16; ++r) z[r] = fmaf(cIs[st], dv[r], cA * A[r]);
    R = matmul_hb(FP, FB, z);
    if (st < 2) FP = convert_h(R);
  }

  // ---- squarings: straight-line for s=2 and s=3 (typical); loop fallback ----
  if (s == 2) {
    FragH H = convert_h(R);
    R = sq_h(H, z0);
    H = convert_h(R);
    R = sq_h(H, z0);
  } else if (s == 3) {
    Frag FQ = convert(R);
    R = matmul(FQ, FQ, z0);
    FragH H = convert_h(R);
    R = sq_h(H, z0);
    H = convert_h(R);
    R = sq_h(H, z0);
  } else {
    for (int i = 0; i < s; ++i) {
      if (s - i > 2) {
        Frag FQ = convert(R);
        R = matmul(FQ, FQ, z0);
      } else {
        FragH H = convert_h(R);
        R = sq_h(H, z0);
      }
    }
  }

  // ---- store (transpose of C-layout via symmetry; mirrors load), nontemporal ----
#pragma unroll
  for (int g = 0; g < 4; ++g) {
    f32x4 wv;
    wv.x = R[4 * g + 0]; wv.y = R[4 * g + 1];
    wv.z = R[4 * g + 2]; wv.w = R[4 * g + 3];
    __builtin_nontemporal_store(wv, (f32x4*)(dst + (size_t)(c32 * 32 + g * 8 + hi * 4)));
  }
}

extern "C" void kernel_launch(void* const* d_in, const int* in_sizes, int n_in,
                              void* d_out, int out_size, void* d_ws, size_t ws_size,
                              hipStream_t stream) {
  const float* in = (const float*)d_in[0];
  float* out = (float*)d_out;
  const int nmat = in_sizes[0] >> 10;
  const int blocks = (nmat + NW - 1) / NW;
  expm32_kernel<<<blocks, 256, 0, stream>>>(in, out, nmat);
}

// Round 15
// 99.597 us; speedup vs baseline: 1.0664x; 1.0664x over previous
//
#include <hip/hip_runtime.h>
#include <math.h>

#define NW 4  // waves per block; one matrix per wave

typedef __attribute__((ext_vector_type(16))) float f32x16;
typedef __attribute__((ext_vector_type(4))) float f32x4;
typedef __attribute__((ext_vector_type(8))) short s16x8;
typedef __attribute__((ext_vector_type(4))) unsigned int u32x4;

struct Frag { s16x8 h0, h1, l0, l1; };  // bf16 hi/lo, k-halves 0..15 / 16..31
struct FragH { s16x8 h0, h1; };         // bf16 RNE hi only

__device__ __forceinline__ f32x16 mfma32(s16x8 a, s16x8 b, f32x16 c) {
  return __builtin_amdgcn_mfma_f32_32x32x16_bf16(a, b, c, 0, 0, 0);
}

// Full split product: XhYh + XhYl + XlYh (rel ~2^-17)
__device__ __forceinline__ f32x16 matmul(const Frag& X, const Frag& Y, f32x16 acc) {
  acc = mfma32(X.h0, Y.h0, acc);
  acc = mfma32(X.h1, Y.h1, acc);
  acc = mfma32(X.h0, Y.l0, acc);
  acc = mfma32(X.h1, Y.l1, acc);
  acc = mfma32(X.l0, Y.h0, acc);
  acc = mfma32(X.l1, Y.h1, acc);
  return acc;
}

// Half-split product: Xh(Yh+Yl) — X's lo dropped (X's weight in result is small)
__device__ __forceinline__ f32x16 matmul_hb(const FragH& X, const Frag& Y, f32x16 acc) {
  acc = mfma32(X.h0, Y.h0, acc);
  acc = mfma32(X.h1, Y.h1, acc);
  acc = mfma32(X.h0, Y.l0, acc);
  acc = mfma32(X.h1, Y.l1, acc);
  return acc;
}

// RNE-bf16-only squaring (rel ~2^-8; last squarings only)
__device__ __forceinline__ f32x16 sq_h(const FragH& X, f32x16 acc) {
  acc = mfma32(X.h0, X.h0, acc);
  acc = mfma32(X.h1, X.h1, acc);
  return acc;
}

__device__ __forceinline__ s16x8 mk(uint a, uint b, uint c, uint d) {
  union { u32x4 u; s16x8 s; } t;
  t.u = (u32x4){a, b, c, d};
  return t.s;
}

// C/D layout (col=lane&31, row=(reg&3)+8*(reg>>2)+4*hi) -> A/B fragment
// (row=lane&31, k contiguous) via symmetry; 8 permlane32_swap, both outputs used.
__device__ __forceinline__ void permstage(const f32x16 c, uint e[16]) {
#pragma unroll
  for (int f = 0; f < 2; ++f)
#pragma unroll
    for (int j = 0; j < 4; ++j) {
      auto r = __builtin_amdgcn_permlane32_swap(
          __float_as_uint(c[8 * f + 4 + j]), __float_as_uint(c[8 * f + j]),
          false, false);
      e[8 * f + j] = r[1];
      e[8 * f + 4 + j] = r[0];
    }
}

// Full split convert: hi = RNE bf16 (cvt_pk), lo = RNE(residual)
__device__ __forceinline__ Frag convert(const f32x16 c) {
  uint e[16];
  permstage(c, e);
  uint hw[8], lw[8];
#pragma unroll
  for (int p = 0; p < 8; ++p) {
    float x0 = __uint_as_float(e[2 * p]);
    float x1 = __uint_as_float(e[2 * p + 1]);
    uint hp;
    asm("v_cvt_pk_bf16_f32 %0, %1, %2" : "=v"(hp) : "v"(x0), "v"(x1));
    float l0 = x0 - __uint_as_float(hp << 16);
    float l1 = x1 - __uint_as_float(hp & 0xffff0000u);
    uint lp;
    asm("v_cvt_pk_bf16_f32 %0, %1, %2" : "=v"(lp) : "v"(l0), "v"(l1));
    hw[p] = hp;
    lw[p] = lp;
  }
  Frag F;
  F.h0 = mk(hw[0], hw[1], hw[2], hw[3]);
  F.h1 = mk(hw[4], hw[5], hw[6], hw[7]);
  F.l0 = mk(lw[0], lw[1], lw[2], lw[3]);
  F.l1 = mk(lw[4], lw[5], lw[6], lw[7]);
  return F;
}

// Cheap convert: RNE bf16 hi only
__device__ __forceinline__ FragH convert_h(const f32x16 c) {
  uint e[16];
  permstage(c, e);
  uint hw[8];
#pragma unroll
  for (int p = 0; p < 8; ++p) {
    float x0 = __uint_as_float(e[2 * p]);
    float x1 = __uint_as_float(e[2 * p + 1]);
    uint hp;
    asm("v_cvt_pk_bf16_f32 %0, %1, %2" : "=v"(hp) : "v"(x0), "v"(x1));
    hw[p] = hp;
  }
  FragH F;
  F.h0 = mk(hw[0], hw[1], hw[2], hw[3]);
  F.h1 = mk(hw[4], hw[5], hw[6], hw[7]);
  return F;
}

// Load A in C-layout via symmetry: reg 4g+q <- A[c32][8g+4hi+q]
__device__ __forceinline__ f32x16 loadA(const float* __restrict__ p, uint c32, uint hi) {
  f32x16 A;
#pragma unroll
  for (int g = 0; g < 4; ++g) {
    float4 v = *(const float4*)(p + c32 * 32 + g * 8 + hi * 4);
    A[4 * g + 0] = v.x; A[4 * g + 1] = v.y; A[4 * g + 2] = v.z; A[4 * g + 3] = v.w;
  }
  return A;
}

__global__ __launch_bounds__(256, 4) void expm32_kernel(const float* __restrict__ in,
                                                        float* __restrict__ out, int nmat) {
  const uint lane = threadIdx.x & 63;
  const uint wid = threadIdx.x >> 6;
  const uint c32 = lane & 31, hi = lane >> 5;
  const uint m = blockIdx.x * NW + wid;
  if (m >= (uint)nmat) return;
  const float* src = in + (size_t)m * 1024u;
  float* dst = out + (size_t)m * 1024u;

  // Diagonal mask vector (one reg per lane when hi matches)
  const uint rd = (c32 & 3) | ((c32 >> 1) & 12);
  const bool dval = (hi == ((c32 >> 2) & 1));
  f32x16 dv;
#pragma unroll
  for (int r = 0; r < 16; ++r) dv[r] = (dval && (uint)r == rd) ? 1.f : 0.f;

  f32x16 A = loadA(src, c32, hi);

  // ---- A2 = A*A (unscaled, full split precision) ----
  Frag FA = convert(A);
  f32x16 z0;
#pragma unroll
  for (int r = 0; r < 16; ++r) z0[r] = 0.f;
  f32x16 A2 = matmul(FA, FA, z0);

  // ---- ||A2||_F^2 -> s (branchless): lambda^4 <= ||A2||_F^2; lam/2^s <= theta=3
  float ss2 = 0.f;
#pragma unroll
  for (int r = 0; r < 16; ++r) ss2 = fmaf(A2[r], A2[r], ss2);
#pragma unroll
  for (int o = 32; o > 0; o >>= 1) ss2 += __shfl_xor(ss2, o, 64);
  int s;
  {
    float v = ss2 * (1.f / 81.f);  // / theta^4
    uint u = __float_as_uint(v);
    int e = (int)((u >> 23) & 255) - 127 + (((u & 0x7fffffu) != 0u) ? 1 : 0);
    s = (e + 3) >> 2;  // ceil(e/4): 16^s >= v
    s = (s < 0) ? 0 : (s > 15 ? 15 : s);
  }
  const float sc = __uint_as_float((uint)(127 - s) << 23);  // exact 2^-s
  const float sc2 = sc * sc;

  // ---- FB = frag(A2') [split]; P3 = c6 I + c7 A' + c8 A2' [cheap] ----
  f32x16 B2;
#pragma unroll
  for (int r = 0; r < 16; ++r) B2[r] = A2[r] * sc2;
  Frag FB = convert(B2);
  const float c7s = (1.f / 5040.f) * sc, c8f = 1.f / 40320.f;
  f32x16 z;
#pragma unroll
  for (int r = 0; r < 16; ++r)
    z[r] = fmaf(c8f, B2[r], fmaf(c7s, A[r], (1.f / 720.f) * dv[r]));
  FragH FP = convert_h(z);  // P3 weight ~0.002 -> lo-drop contributes <~2 abs

  // ---- 3 Horner steps: P <- Ph*A2' + cI*I + cA*A' (hi-only P operand) ----
  const float cIs[3] = {1.f / 24.f, 0.5f, 1.f};
  const float cAs[3] = {1.f / 120.f, 1.f / 6.f, 1.f};
  f32x16 R;
#pragma unroll
  for (int st = 0; st < 3; ++st) {
    const float cA = cAs[st] * sc;
#pragma unroll
    for (int r = 0; r < 16; ++r) z[r] = fmaf(cIs[st], dv[r], cA * A[r]);
    R = matmul_hb(FP, FB, z);
    if (st < 2) FP = convert_h(R);
  }

  // ---- squarings: straight-line for s=2 (typical) and s=3; loop fallback ----
  if (s == 2) {
    FragH H = convert_h(R);
    R = sq_h(H, z0);
    H = convert_h(R);
    R = sq_h(H, z0);
  } else if (s == 3) {
    Frag FQ = convert(R);
    R = matmul(FQ, FQ, z0);
    FragH H = convert_h(R);
    R = sq_h(H, z0);
    H = convert_h(R);
    R = sq_h(H, z0);
  } else {
    for (int i = 0; i < s; ++i) {
      if (s - i > 2) {
        Frag FQ = convert(R);
        R = matmul(FQ, FQ, z0);
      } else {
        FragH H = convert_h(R);
        R = sq_h(H, z0);
      }
    }
  }

  // ---- store (transpose of C-layout via symmetry; mirrors load), nontemporal ----
#pragma unroll
  for (int g = 0; g < 4; ++g) {
    f32x4 wv;
    wv.x = R[4 * g + 0]; wv.y = R[4 * g + 1];
    wv.z = R[4 * g + 2]; wv.w = R[4 * g + 3];
    __builtin_nontemporal_store(wv, (f32x4*)(dst + (size_t)(c32 * 32 + g * 8 + hi * 4)));
  }
}

extern "C" void kernel_launch(void* const* d_in, const int* in_sizes, int n_in,
                              void* d_out, int out_size, void* d_ws, size_t ws_size,
                              hipStream_t stream) {
  const float* in = (const float*)d_in[0];
  float* out = (float*)d_out;
  const int nmat = in_sizes[0] >> 10;
  const int blocks = (nmat + NW - 1) / NW;
  expm32_kernel<<<blocks, 256, 0, stream>>>(in, out, nmat);
}